// Round 6
// baseline (584.890 us; speedup 1.0000x reference)
//
#include <hip/hip_runtime.h>

// Problem dims (fixed).
#define BB 512
#define TT 1024
#define DD 64
#define HH 64
#define BT (BB * TT)    // 524288
#define Y_SIZE (BB * TT * HH)  // 33554432

typedef _Float16 half8 __attribute__((ext_vector_type(8)));
typedef _Float16 half4 __attribute__((ext_vector_type(4)));
typedef float f32x4 __attribute__((ext_vector_type(4)));

#define MFMA16(a, b, c) __builtin_amdgcn_mfma_f32_16x16x32_f16((a), (b), (c), 0, 0, 0)

// Raw workgroup barrier draining ONLY lgkmcnt (LDS); y stores and x prefetch
// loads stay in flight (R2: +2%). All cross-wave data is LDS.
__device__ __forceinline__ void wg_barrier_lds() {
    asm volatile("s_waitcnt lgkmcnt(0)" ::: "memory");
    __builtin_amdgcn_s_barrier();
    asm volatile("" ::: "memory");
}

__device__ __forceinline__ float sigm(float x) {
    return __builtin_amdgcn_rcpf(1.0f + __expf(-x));
}
__device__ __forceinline__ float tanh_(float x) {
    return 1.0f - 2.0f * __builtin_amdgcn_rcpf(1.0f + __expf(2.0f * x));
}

// lane l <-> lane l^16 exchange (BitMode xor-16; within 32-lane halves, and
// l^16 stays within the same half for all l). lgkm-tracked.
__device__ __forceinline__ float swz16(float x) {
    return __int_as_float(
        __builtin_amdgcn_ds_swizzle(__float_as_int(x), 0x401F));
}

__device__ __forceinline__ half8 cvt8(f32x4 a, f32x4 b) {
    half8 h;
    h[0] = (_Float16)a[0]; h[1] = (_Float16)a[1];
    h[2] = (_Float16)a[2]; h[3] = (_Float16)a[3];
    h[4] = (_Float16)b[0]; h[5] = (_Float16)b[1];
    h[6] = (_Float16)b[2]; h[7] = (_Float16)b[3];
    return h;
}

// ---------------------------------------------------------------------------
// LSTM kernel: 256 WGs (2 batch rows each), 256 threads (4 waves), 1 WG/CU.
// [R1: 2 WGs/CU regressed. R2: lgkm barrier +2%. R3: x-pipelining +2%
//  (BEST base, 316.7us). R4: fusion regressed. R5: xg-hoist regressed
//  slightly -> step time invariant to MFMA count; VALUBusy ~38% dominated by
//  10 quarter-rate transcendentals/step computed redundantly on dup lanes.
//  R6: ACT-DEDUP — quads 1,3 hold bit-identical gate pre-acts to quads 0,2
//  (A rows 0-7 are replicas => D rows identical). Split: hi-lanes compute
//  {g-tanh, o-sigm}, lo-lanes {i-sigm, f-sigm} via shared wave-wide exp/rcp
//  with lane-selected inputs; exchange via 2 ds_swizzle (l^16). 10->6
//  quarter-rate instrs. Writer-lane math bit-identical to the old path.]
// Also stores f16 y copy to workspace (if provided) for the heads kernel.
// ---------------------------------------------------------------------------
__global__ __launch_bounds__(256) void lstm_kernel(
    const float* __restrict__ x, const float* __restrict__ h_init,
    const float* __restrict__ c_init, const float* __restrict__ W_ih,
    const float* __restrict__ W_hh, const float* __restrict__ b_ih,
    const float* __restrict__ b_hh, float* __restrict__ y,
    _Float16* __restrict__ y16)
{
    __shared__ alignas(16) _Float16 xch[2][16][2][DD];  // x chunks, f16, dbuf
    __shared__ alignas(16) _Float16 hst[2][2][HH];      // h stage, dbuf

    const int tid  = threadIdx.x;
    const int wave = tid >> 6;
    const int lane = tid & 63;
    const int col  = lane & 15;
    const int quad = lane >> 4;
    const int sel  = (lane >> 3) & 1;       // batch row this lane feeds as A
    const int r_act = lane >> 5;            // batch row this lane's unit belongs to
    const int j    = (wave << 4) + col;     // hidden unit index [0,64)
    const int hi   = quad & 1;              // 1 = dup half (quads 1,3)
    const bool writer = (hi == 0);          // quads 0,2 own the write

    const int b0 = blockIdx.x * 2;

    // ---- resident weight fragments: B[k][n] = Wcat[n][k] (f16) ----
    half8 bf[4][4];
    f32x4 biasv[4];
#pragma unroll
    for (int G = 0; G < 4; ++G) {
        const int n = (G << 6) + j;
        const float bs = b_ih[n] + b_hh[n];
        biasv[G][0] = bs; biasv[G][1] = bs; biasv[G][2] = bs; biasv[G][3] = bs;
#pragma unroll
        for (int c = 0; c < 4; ++c) {
            const float* src = (c < 2) ? (W_ih + n * DD + c * 32 + quad * 8)
                                       : (W_hh + n * HH + (c - 2) * 32 + quad * 8);
            f32x4 w0 = *(const f32x4*)src;
            f32x4 w1 = *(const f32x4*)(src + 4);
            bf[G][c] = cvt8(w0, w1);
        }
    }

    float c_state = c_init[j];

    // ---- init h stage (buffer 0) + first x chunk ----
    if (tid < 128) {
        const int rr = tid >> 6, jj = tid & 63;
        hst[0][rr][jj] = (_Float16)h_init[jj];
    }
    {
        const int ss = tid >> 4, rr = (tid >> 3) & 1, j0 = (tid & 7) << 3;
        const float* src = x + ((b0 + rr) * TT + ss) * DD + j0;
        f32x4 g0 = *(const f32x4*)src;
        f32x4 g1 = *(const f32x4*)(src + 4);
        *(half8*)&xch[0][ss][rr][j0] = cvt8(g0, g1);
    }
    wg_barrier_lds();

    const int ss_pf = tid >> 4, rr_pf = (tid >> 3) & 1, j0_pf = (tid & 7) << 3;

    // ---- x-part pipeline prologue: xacc for t=0 ----
    f32x4 xacc0, xacc1, xacc2, xacc3;
    {
        const _Float16* xrow = &xch[0][0][sel][0];
        half8 a0 = *(const half8*)(xrow + quad * 8);
        half8 a1 = *(const half8*)(xrow + 32 + quad * 8);
        xacc0 = MFMA16(a0, bf[0][0], biasv[0]); xacc0 = MFMA16(a1, bf[0][1], xacc0);
        xacc1 = MFMA16(a0, bf[1][0], biasv[1]); xacc1 = MFMA16(a1, bf[1][1], xacc1);
        xacc2 = MFMA16(a0, bf[2][0], biasv[2]); xacc2 = MFMA16(a1, bf[2][1], xacc2);
        xacc3 = MFMA16(a0, bf[3][0], biasv[3]); xacc3 = MFMA16(a1, bf[3][1], xacc3);
    }

    for (int ci = 0; ci < 64; ++ci) {
        const int buf = ci & 1;
        const bool pf = (ci + 1) < 64;
        f32x4 g0, g1;
        if (pf) {  // prefetch next 16-step x chunk (lands at s==14)
            const float* src = x + ((b0 + rr_pf) * TT + ((ci + 1) << 4) + ss_pf) * DD + j0_pf;
            g0 = *(const f32x4*)src;
            g1 = *(const f32x4*)(src + 4);
        }
#pragma unroll
        for (int s = 0; s < 16; ++s) {
            const int t = (ci << 4) + s;
            const int p = s & 1;

            // h-part: 2-deep MFMA chain on precomputed xacc [critical]
            const _Float16* hrow = &hst[p][sel][0];
            half8 a2 = *(const half8*)(hrow + quad * 8);
            half8 a3 = *(const half8*)(hrow + 32 + quad * 8);
            f32x4 acc0 = MFMA16(a2, bf[0][2], xacc0);
            f32x4 acc1 = MFMA16(a2, bf[1][2], xacc1);
            f32x4 acc2 = MFMA16(a2, bf[2][2], xacc2);
            f32x4 acc3 = MFMA16(a2, bf[3][2], xacc3);
            acc0 = MFMA16(a3, bf[0][3], acc0); acc1 = MFMA16(a3, bf[1][3], acc1);
            acc2 = MFMA16(a3, bf[2][3], acc2); acc3 = MFMA16(a3, bf[3][3], acc3);

            // next step's x-part (independent; fills matrix pipe under VALU)
            if (t < TT - 1) {
                const _Float16* nx = (s < 15) ? &xch[buf][s + 1][sel][0]
                                              : &xch[buf ^ 1][0][sel][0];
                half8 a0 = *(const half8*)(nx + quad * 8);
                half8 a1 = *(const half8*)(nx + 32 + quad * 8);
                xacc0 = MFMA16(a0, bf[0][0], biasv[0]); xacc0 = MFMA16(a1, bf[0][1], xacc0);
                xacc1 = MFMA16(a0, bf[1][0], biasv[1]); xacc1 = MFMA16(a1, bf[1][1], xacc1);
                xacc2 = MFMA16(a0, bf[2][0], biasv[2]); xacc2 = MFMA16(a1, bf[2][1], xacc2);
                xacc3 = MFMA16(a0, bf[3][0], biasv[3]); xacc3 = MFMA16(a1, bf[3][1], xacc3);
            }

            // ---- act-dedup: lo lanes (hi=0) do i,f sigmoids; hi lanes do
            // g-tanh, o-sigmoid; shared wave-wide exp/rcp; swz16 exchange.
            // i: rcp(1+exp(-x))   g: 1-2*rcp(1+exp(2x))   f,o: sigmoid
            const float ua = hi ? (2.0f * acc2[0]) : (-acc0[0]);
            const float ea = __expf(ua);
            float av = __builtin_amdgcn_rcpf(1.0f + ea);
            av = hi ? fmaf(-2.0f, av, 1.0f) : av;       // {si | tg}
            const float vb = hi ? acc3[0] : acc1[0];
            const float eb = __expf(-vb);
            const float bv = __builtin_amdgcn_rcpf(1.0f + eb);  // {sf | so}
            const float av_sw = swz16(av);  // writer gets tg
            const float bv_sw = swz16(bv);  // writer gets so
            // writers: si=av, sf=bv, tg=av_sw, so=bv_sw (bit-identical math;
            // non-writer lanes compute garbage c_state, never read)
            c_state = bv * c_state + av * av_sw;
            const float hv = bv_sw * tanh_(c_state);
            if (writer) {
                const _Float16 hvh = (_Float16)hv;
                hst[p ^ 1][r_act][j] = hvh;
                y[((b0 + r_act) * TT + t) * HH + j] = hv;  // in flight
                if (y16) y16[((b0 + r_act) * TT + t) * HH + j] = hvh;
            }
            if (s == 14 && pf) {  // land prefetched chunk
                *(half8*)&xch[buf ^ 1][ss_pf][rr_pf][j0_pf] = cvt8(g0, g1);
            }
            wg_barrier_lds();  // lgkm-only: hst/xch/swizzles ordered; stores fly
        }
    }
}

// ---------------------------------------------------------------------------
// Heads (f16-input): 2048 WGs x 256 threads, ZERO barriers. Each wave owns
// 4 tiles of 16 rows; A-frags straight from the f16 y copy (no cvt, half the
// fetch bytes of the f32 path). Per-wave LDS transpose buffers, no parity
// (per-wave DS ops are in-order => no WAR hazard). L3 = block-diag MFMA.
// ---------------------------------------------------------------------------
__global__ __launch_bounds__(256) void heads_kernel_f16(
    const _Float16* __restrict__ y16,
    const float* __restrict__ W1, const float* __restrict__ b1,
    const float* __restrict__ W2, const float* __restrict__ b2,
    const float* __restrict__ W3, const float* __restrict__ b3,
    float* __restrict__ outs)
{
    __shared__ alignas(16) _Float16 h1w[4][16][144];
    __shared__ alignas(16) _Float16 h2w[4][16][144];

    const int tid  = threadIdx.x;
    const int wave = tid >> 6;
    const int lane = tid & 63;
    const int col  = lane & 15;
    const int quad = lane >> 4;

    half8 w1f[8][2]; float bias1[8];
#pragma unroll
    for (int nt = 0; nt < 8; ++nt) {
        const int n = nt * 16 + col;
        bias1[nt] = b1[n];
#pragma unroll
        for (int c = 0; c < 2; ++c) {
            const float* src = W1 + n * 64 + c * 32 + quad * 8;
            w1f[nt][c] = cvt8(*(const f32x4*)src, *(const f32x4*)(src + 4));
        }
    }
    half8 w2f[8]; float bias2[8];
#pragma unroll
    for (int nt = 0; nt < 8; ++nt) {
        const int n = nt * 16 + col;
        bias2[nt] = b2[n];
        const float* src = W2 + n * 32 + quad * 8;
        w2f[nt] = cvt8(*(const f32x4*)src, *(const f32x4*)(src + 4));
    }
    half8 b3f[4];
    {
        const float* src = W3 + (col < 4 ? col * 32 : 0) + quad * 8;
        half8 wv = cvt8(*(const f32x4*)src, *(const f32x4*)(src + 4));
        half8 hz;
#pragma unroll
        for (int i = 0; i < 8; ++i) hz[i] = (_Float16)0.0f;
#pragma unroll
        for (int kc = 0; kc < 4; ++kc)
            b3f[kc] = (col == kc) ? wv : hz;
    }
    const float b3v = (col < 4) ? b3[col] : 0.0f;

    const long wbase = (long)blockIdx.x * 256 + wave * 64;

    half8 ga0 = *(const half8*)(y16 + (wbase + col) * 64 + quad * 8);
    half8 ga1 = *(const half8*)(y16 + (wbase + col) * 64 + 32 + quad * 8);

#pragma unroll
    for (int tb = 0; tb < 4; ++tb) {
        half8 a0 = ga0, a1 = ga1;
        if (tb < 3) {
            const _Float16* src = y16 + (wbase + (tb + 1) * 16 + col) * 64 + quad * 8;
            ga0 = *(const half8*)src;
            ga1 = *(const half8*)(src + 32);
        }
#pragma unroll
        for (int nt = 0; nt < 8; ++nt) {
            f32x4 acc = {bias1[nt], bias1[nt], bias1[nt], bias1[nt]};
            acc = MFMA16(a0, w1f[nt][0], acc);
            acc = MFMA16(a1, w1f[nt][1], acc);
#pragma unroll
            for (int r = 0; r < 4; ++r) {
                float v = acc[r] > 0.0f ? acc[r] : 0.0f;
                h1w[wave][(quad << 2) + r][nt * 16 + col] = (_Float16)v;
            }
        }
        half8 ah[4];
#pragma unroll
        for (int hd = 0; hd < 4; ++hd)
            ah[hd] = *(const half8*)&h1w[wave][col][hd * 32 + quad * 8];
#pragma unroll
        for (int nt = 0; nt < 8; ++nt) {
            f32x4 acc = {bias2[nt], bias2[nt], bias2[nt], bias2[nt]};
            acc = MFMA16(ah[nt >> 1], w2f[nt], acc);
#pragma unroll
            for (int r = 0; r < 4; ++r) {
                float v = acc[r] > 0.0f ? acc[r] : 0.0f;
                h2w[wave][(quad << 2) + r][nt * 16 + col] = (_Float16)v;
            }
        }
        f32x4 d = {b3v, b3v, b3v, b3v};
#pragma unroll
        for (int kc = 0; kc < 4; ++kc) {
            half8 av = *(const half8*)&h2w[wave][col][kc * 32 + quad * 8];
            d = MFMA16(av, b3f[kc], d);
        }
        if (col < 4)
            *(f32x4*)(outs + (long)col * BT + wbase + tb * 16 + quad * 4) = d;
    }
}

// f32-input fallback (no workspace): identical structure, cvt on load.
__global__ __launch_bounds__(256) void heads_kernel_f32(
    const float* __restrict__ y,
    const float* __restrict__ W1, const float* __restrict__ b1,
    const float* __restrict__ W2, const float* __restrict__ b2,
    const float* __restrict__ W3, const float* __restrict__ b3,
    float* __restrict__ outs)
{
    __shared__ alignas(16) _Float16 h1w[4][16][144];
    __shared__ alignas(16) _Float16 h2w[4][16][144];

    const int tid  = threadIdx.x;
    const int wave = tid >> 6;
    const int lane = tid & 63;
    const int col  = lane & 15;
    const int quad = lane >> 4;

    half8 w1f[8][2]; float bias1[8];
#pragma unroll
    for (int nt = 0; nt < 8; ++nt) {
        const int n = nt * 16 + col;
        bias1[nt] = b1[n];
#pragma unroll
        for (int c = 0; c < 2; ++c) {
            const float* src = W1 + n * 64 + c * 32 + quad * 8;
            w1f[nt][c] = cvt8(*(const f32x4*)src, *(const f32x4*)(src + 4));
        }
    }
    half8 w2f[8]; float bias2[8];
#pragma unroll
    for (int nt = 0; nt < 8; ++nt) {
        const int n = nt * 16 + col;
        bias2[nt] = b2[n];
        const float* src = W2 + n * 32 + quad * 8;
        w2f[nt] = cvt8(*(const f32x4*)src, *(const f32x4*)(src + 4));
    }
    half8 b3f[4];
    {
        const float* src = W3 + (col < 4 ? col * 32 : 0) + quad * 8;
        half8 wv = cvt8(*(const f32x4*)src, *(const f32x4*)(src + 4));
        half8 hz;
#pragma unroll
        for (int i = 0; i < 8; ++i) hz[i] = (_Float16)0.0f;
#pragma unroll
        for (int kc = 0; kc < 4; ++kc)
            b3f[kc] = (col == kc) ? wv : hz;
    }
    const float b3v = (col < 4) ? b3[col] : 0.0f;

    const long wbase = (long)blockIdx.x * 256 + wave * 64;

    f32x4 ga0, ga1, ga2, ga3;
    {
        const float* src = y + (wbase + col) * 64 + quad * 8;
        ga0 = *(const f32x4*)src;        ga1 = *(const f32x4*)(src + 4);
        ga2 = *(const f32x4*)(src + 32); ga3 = *(const f32x4*)(src + 36);
    }

#pragma unroll
    for (int tb = 0; tb < 4; ++tb) {
        half8 a0 = cvt8(ga0, ga1);
        half8 a1 = cvt8(ga2, ga3);
        if (tb < 3) {
            const float* src = y + (wbase + (tb + 1) * 16 + col) * 64 + quad * 8;
            ga0 = *(const f32x4*)src;        ga1 = *(const f32x4*)(src + 4);
            ga2 = *(const f32x4*)(src + 32); ga3 = *(const f32x4*)(src + 36);
        }
#pragma unroll
        for (int nt = 0; nt < 8; ++nt) {
            f32x4 acc = {bias1[nt], bias1[nt], bias1[nt], bias1[nt]};
            acc = MFMA16(a0, w1f[nt][0], acc);
            acc = MFMA16(a1, w1f[nt][1], acc);
#pragma unroll
            for (int r = 0; r < 4; ++r) {
                float v = acc[r] > 0.0f ? acc[r] : 0.0f;
                h1w[wave][(quad << 2) + r][nt * 16 + col] = (_Float16)v;
            }
        }
        half8 ah[4];
#pragma unroll
        for (int hd = 0; hd < 4; ++hd)
            ah[hd] = *(const half8*)&h1w[wave][col][hd * 32 + quad * 8];
#pragma unroll
        for (int nt = 0; nt < 8; ++nt) {
            f32x4 acc = {bias2[nt], bias2[nt], bias2[nt], bias2[nt]};
            acc = MFMA16(ah[nt >> 1], w2f[nt], acc);
#pragma unroll
            for (int r = 0; r < 4; ++r) {
                float v = acc[r] > 0.0f ? acc[r] : 0.0f;
                h2w[wave][(quad << 2) + r][nt * 16 + col] = (_Float16)v;
            }
        }
        f32x4 d = {b3v, b3v, b3v, b3v};
#pragma unroll
        for (int kc = 0; kc < 4; ++kc) {
            half8 av = *(const half8*)&h2w[wave][col][kc * 32 + quad * 8];
            d = MFMA16(av, b3f[kc], d);
        }
        if (col < 4)
            *(f32x4*)(outs + (long)col * BT + wbase + tb * 16 + quad * 4) = d;
    }
}

extern "C" void kernel_launch(void* const* d_in, const int* in_sizes, int n_in,
                              void* d_out, int out_size, void* d_ws, size_t ws_size,
                              hipStream_t stream) {
    (void)in_sizes; (void)n_in; (void)out_size;
    const float* x      = (const float*)d_in[0];
    const float* h_init = (const float*)d_in[1];
    const float* c_init = (const float*)d_in[2];
    const float* W_ih   = (const float*)d_in[3];
    const float* W_hh   = (const float*)d_in[4];
    const float* b_ih   = (const float*)d_in[5];
    const float* b_hh   = (const float*)d_in[6];
    const float* W1     = (const float*)d_in[7];
    const float* b1     = (const float*)d_in[8];
    const float* W2     = (const float*)d_in[9];
    const float* b2     = (const float*)d_in[10];
    const float* W3     = (const float*)d_in[11];
    const float* b3     = (const float*)d_in[12];
    float* y    = (float*)d_out;
    float* outs = y + Y_SIZE;

    // f16 y copy lives in workspace when it's big enough (67.1 MB needed).
    const bool use16 = (d_ws != nullptr) && (ws_size >= (size_t)Y_SIZE * 2);
    _Float16* y16 = use16 ? (_Float16*)d_ws : nullptr;

    lstm_kernel<<<dim3(256), dim3(256), 0, stream>>>(x, h_init, c_init, W_ih, W_hh,
                                                     b_ih, b_hh, y, y16);
    if (use16)
        heads_kernel_f16<<<dim3(2048), dim3(256), 0, stream>>>(y16, W1, b1, W2, b2,
                                                               W3, b3, outs);
    else
        heads_kernel_f32<<<dim3(2048), dim3(256), 0, stream>>>(y, W1, b1, W2, b2,
                                                               W3, b3, outs);
}